// Round 5
// baseline (529.800 us; speedup 1.0000x reference)
//
#include <hip/hip_runtime.h>
#include <stdint.h>

// GraphConvolution: out[0:8192]    = deg[i]     *(adj  @ (v@Wv)) + bias
//                   out[8192:16k]  = deg[8192+j]*(adjT @ (u@Wu)) + bias
// R5 (467us): packed-B fragment layout. R6 (489, FAILED): prefetch+occupancy.
// R7: fused single-pass 256x256 tiles. Theory: all prior variants were
// DRAM-activation-bound (128-256B per 32KB-strided row-visit, ~2M
// activations ~ 180us). Here EVERY adj access is a contiguous 1KB
// wave-load; adj read exactly once; tile staged to LDS (bf16, XOR-swizzled)
// feeds BOTH top (waves 0-1, rows) and bot (waves 2-3, cols) partials.
// Partials -> ws (sequential), k_fin reduces 32 chunks + degree/bias.
// (R8 = R7 resubmitted unchanged: round 4 bench died on GPU acquisition
// timeout, no signal obtained.)

#define HID 64
#define IN_DIM 128
#define NROWS 8192
#define NCLS 5

typedef float f32x4 __attribute__((ext_vector_type(4)));
typedef short s16x8 __attribute__((ext_vector_type(8)));
typedef short s16x4 __attribute__((ext_vector_type(4)));
typedef unsigned short u16;

// packed side size: 256 kb * 4 nb * 64 lane * 8 e = 524288 u16 = 1 MiB
#define PACK_SIDE 524288

static __device__ __forceinline__ short f2b(float x) {  // RNE fp32->bf16
    unsigned u = __builtin_bit_cast(unsigned, x);
    return (short)((u + 0x7FFFu + ((u >> 16) & 1u)) >> 16);
}

// ---------------------------------------------------------------------------
// k_prep: W = sum_{c<=r} weight[c]; s = X @ W; store B-fragment-packed bf16:
// pack[kb][nb][lane][e] = s[row = kb*32 + (lane>>4)*8 + e][h = nb*16 + (lane&15)]
// grid (128, 2): y=0 -> pu (from u), y=1 -> pv (from v). block 256.
// ---------------------------------------------------------------------------
__global__ __launch_bounds__(256, 2) void k_prep(
    const float* __restrict__ u, const float* __restrict__ v,
    const float* __restrict__ uw, const float* __restrict__ vw,
    const int* __restrict__ rp, u16* __restrict__ ws)
{
    __shared__ float W[IN_DIM * HID];
    __shared__ float X[64 * 129];

    const int y = blockIdx.y;
    const float* __restrict__ src  = y ? v  : u;
    const float* __restrict__ wsrc = y ? vw : uw;
    u16* __restrict__ dstP = ws + (size_t)y * PACK_SIDE;
    const int i0 = blockIdx.x * 64;
    const int t = threadIdx.x;
    int r = *rp; if (r > NCLS - 1) r = NCLS - 1; if (r < 0) r = 0;

    for (int idx = t; idx < IN_DIM * HID; idx += 256) {
        float s = 0.f;
        for (int c = 0; c <= r; ++c) s += wsrc[c * (IN_DIM * HID) + idx];
        W[idx] = s;
    }
    #pragma unroll
    for (int qq = 0; qq < 8; ++qq) {       // 64 rows x 32 float4 = 2048
        int idx = t + qq * 256;
        int row = idx >> 5, c4 = idx & 31;
        f32x4 val = *(const f32x4*)&src[(size_t)(i0 + row) * IN_DIM + c4 * 4];
        float* d = &X[row * 129 + c4 * 4];
        d[0] = val[0]; d[1] = val[1]; d[2] = val[2]; d[3] = val[3];
    }
    __syncthreads();

    const int i = t & 63, h0 = (t >> 6) * 16;
    float acc[16];
    #pragma unroll
    for (int k = 0; k < 16; ++k) acc[k] = 0.f;
    for (int c = 0; c < IN_DIM; ++c) {
        float uv = X[i * 129 + c];
        const f32x4* wr = (const f32x4*)&W[c * HID + h0];
        f32x4 w0 = wr[0], w1 = wr[1], w2 = wr[2], w3 = wr[3];
        acc[0]  += uv * w0[0]; acc[1]  += uv * w0[1];
        acc[2]  += uv * w0[2]; acc[3]  += uv * w0[3];
        acc[4]  += uv * w1[0]; acc[5]  += uv * w1[1];
        acc[6]  += uv * w1[2]; acc[7]  += uv * w1[3];
        acc[8]  += uv * w2[0]; acc[9]  += uv * w2[1];
        acc[10] += uv * w2[2]; acc[11] += uv * w2[3];
        acc[12] += uv * w3[0]; acc[13] += uv * w3[1];
        acc[14] += uv * w3[2]; acc[15] += uv * w3[3];
    }
    // packed store: row iL = i0+i fixed per thread; h = h0+hh, h>>4 = h0>>4
    const int iL = i0 + i;
    u16* __restrict__ dp = dstP
        + (((size_t)(iL >> 5) * 4 + (h0 >> 4)) << 9)   // (kb*4 + nb) * 512
        + ((iL >> 3) & 3) * 128                        // (lane>>4) * 16 * 8
        + (iL & 7);                                    // e
    #pragma unroll
    for (int hh = 0; hh < 16; ++hh)
        dp[hh * 8] = (u16)f2b(acc[hh]);                // (lane&15) * 8 step
}

// ---------------------------------------------------------------------------
// k_main: 1024 blocks, block (R,C) = (bx>>5, bx&31) owns adj tile
// [R*256, R*256+256) x [C*256, C*256+256). 4 panels of 64 rows x 256 cols
// staged to LDS bf16 with XOR chunk-swizzle (chunk' = (j>>3) ^ (row&7)).
// Staging: each row = ONE contiguous 1KB wave-load (lane l -> cols 4l..4l+4).
// Waves 0-1: top partials (panel = M-chunk, full K=256; finished per panel,
// streamed to ws_top[C]). Waves 2-3: bot partials (panel = K-chunk of 64;
// accB[8][4] persists across panels; written to ws_bot[R] at end).
// Fragment conventions identical to verified R5 (packed-B, m89 C/D layout).
// ---------------------------------------------------------------------------
__global__ __launch_bounds__(256, 2) void k_main(
    const float* __restrict__ adj, const u16* __restrict__ ws,
    float* __restrict__ wst, float* __restrict__ wsb)
{
    __shared__ u16 P[64][256];    // one panel, bf16, swizzled

    const int bx = blockIdx.x;
    const int R0 = (bx >> 5) * 256, C0 = (bx & 31) * 256;
    const int t = threadIdx.x;
    const int w = t >> 6, l = t & 63;
    const int q = l >> 4, l15 = l & 15;
    const u16* __restrict__ BPl_u = ws + (size_t)l * 8;              // pu (bot)
    const u16* __restrict__ BPl_v = ws + PACK_SIDE + (size_t)l * 8;  // pv (top)

    f32x4 accB[8][4];   // bot: 128 cols per bot-wave, persists across panels
    #pragma unroll
    for (int mt = 0; mt < 8; ++mt)
        #pragma unroll
        for (int nn = 0; nn < 4; ++nn) accB[mt][nn] = (f32x4){0.f, 0.f, 0.f, 0.f};

    for (int p = 0; p < 4; ++p) {
        // ---- stage panel p: rows [p*64, p*64+64) of tile, 1KB per row ----
        {
            const float* __restrict__ src =
                adj + (size_t)(R0 + p * 64 + w * 16) * NROWS + C0 + l * 4;
            #pragma unroll
            for (int rr = 0; rr < 16; rr += 4) {
                f32x4 d0 = *(const f32x4*)(src + (size_t)(rr + 0) * NROWS);
                f32x4 d1 = *(const f32x4*)(src + (size_t)(rr + 1) * NROWS);
                f32x4 d2 = *(const f32x4*)(src + (size_t)(rr + 2) * NROWS);
                f32x4 d3 = *(const f32x4*)(src + (size_t)(rr + 3) * NROWS);
                #pragma unroll
                for (int i = 0; i < 4; ++i) {
                    f32x4 d = (i == 0) ? d0 : (i == 1) ? d1 : (i == 2) ? d2 : d3;
                    const int row = w * 16 + rr + i;
                    s16x4 b;
                    b[0] = f2b(d[0]); b[1] = f2b(d[1]);
                    b[2] = f2b(d[2]); b[3] = f2b(d[3]);
                    // element (row, j): chunk (j>>3)^(row&7), offset j&7
                    *(s16x4*)&P[row][(((l >> 1) ^ (row & 7)) << 3) + ((l & 1) << 2)] = b;
                }
            }
        }
        __syncthreads();

        if (w < 2) {
            // ---- top: rows w*32..w*32+32 of panel, full K=256 ----
            f32x4 accT[2][4];
            #pragma unroll
            for (int mt = 0; mt < 2; ++mt)
                #pragma unroll
                for (int nn = 0; nn < 4; ++nn) accT[mt][nn] = (f32x4){0.f, 0.f, 0.f, 0.f};
            #pragma unroll
            for (int kk = 0; kk < 8; ++kk) {
                const int kb = (C0 >> 5) + kk;
                s16x8 bf[4];
                #pragma unroll
                for (int nn = 0; nn < 4; ++nn)
                    bf[nn] = *(const s16x8*)(BPl_v + ((size_t)(kb * 4 + nn) << 9));
                #pragma unroll
                for (int mt = 0; mt < 2; ++mt) {
                    const int row = w * 32 + mt * 16 + l15;
                    s16x8 af = *(const s16x8*)&P[row][((kk * 4 + q) ^ (row & 7)) << 3];
                    #pragma unroll
                    for (int nn = 0; nn < 4; ++nn)
                        accT[mt][nn] = __builtin_amdgcn_mfma_f32_16x16x32_bf16(
                            af, bf[nn], accT[mt][nn], 0, 0, 0);
                }
            }
            // stream finished 32 rows to ws_top[C][global row][h]
            float* __restrict__ WT = wst + (size_t)(bx & 31) * (NROWS * HID)
                                   + (size_t)(R0 + p * 64 + w * 32) * HID;
            #pragma unroll
            for (int mt = 0; mt < 2; ++mt)
                #pragma unroll
                for (int nn = 0; nn < 4; ++nn)
                    #pragma unroll
                    for (int rg = 0; rg < 4; ++rg)
                        WT[(size_t)(mt * 16 + q * 4 + rg) * HID + nn * 16 + l15] =
                            accT[mt][nn][rg];
        } else {
            // ---- bot: cols (w-2)*128..+128, panel = K-chunk of 64 rows ----
            #pragma unroll
            for (int kk = 0; kk < 2; ++kk) {
                const int kb = (R0 >> 5) + p * 2 + kk;
                s16x8 bf[4];
                #pragma unroll
                for (int nn = 0; nn < 4; ++nn)
                    bf[nn] = *(const s16x8*)(BPl_u + ((size_t)(kb * 4 + nn) << 9));
                #pragma unroll
                for (int mt = 0; mt < 8; ++mt) {
                    const int j = (w - 2) * 128 + mt * 16 + l15;
                    s16x8 af;
                    #pragma unroll
                    for (int tt = 0; tt < 8; ++tt) {
                        const int row = kk * 32 + q * 8 + tt;   // row&7 == tt
                        af[tt] = (short)P[row][(((j >> 3) ^ tt) << 3) + (j & 7)];
                    }
                    #pragma unroll
                    for (int nn = 0; nn < 4; ++nn)
                        accB[mt][nn] = __builtin_amdgcn_mfma_f32_16x16x32_bf16(
                            af, bf[nn], accB[mt][nn], 0, 0, 0);
                }
            }
        }
        __syncthreads();
    }

    if (w >= 2) {
        // bot partial -> ws_bot[R][global col][h]
        float* __restrict__ WB = wsb + (size_t)(bx >> 5) * (NROWS * HID)
                               + (size_t)(C0 + (w - 2) * 128) * HID;
        #pragma unroll
        for (int mt = 0; mt < 8; ++mt)
            #pragma unroll
            for (int nn = 0; nn < 4; ++nn)
                #pragma unroll
                for (int rg = 0; rg < 4; ++rg)
                    WB[(size_t)(mt * 16 + q * 4 + rg) * HID + nn * 16 + l15] =
                        accB[mt][nn][rg];
    }
}

// ---------------------------------------------------------------------------
// k_fin: out[r] = degree[r] * sum_{c<32} ws[c][r][:] + bias. grid 1024:
// blocks 0..511 top (ws_top), 512..1023 bot (ws_bot); 16 rows per block.
// ---------------------------------------------------------------------------
__global__ __launch_bounds__(256, 4) void k_fin(
    const float* __restrict__ degree, const float* __restrict__ bias,
    const float* __restrict__ wst, const float* __restrict__ wsb,
    float* __restrict__ out)
{
    const int b = blockIdx.x;
    const int side = (b >= 512);
    const int t = threadIdx.x;
    const int r = (b & 511) * 16 + (t >> 4);
    const int c4 = (t & 15) * 4;
    const float* __restrict__ W = side ? wsb : wst;

    f32x4 s = (f32x4){0.f, 0.f, 0.f, 0.f};
    #pragma unroll
    for (int c = 0; c < 32; ++c)
        s += *(const f32x4*)&W[(size_t)c * (NROWS * HID) + (size_t)r * HID + c4];
    const int grow = side * NROWS + r;
    const float d = degree[grow];
    f32x4 bb = *(const f32x4*)&bias[c4];
    *(f32x4*)&out[(size_t)grow * HID + c4] = d * s + bb;
}

extern "C" void kernel_launch(void* const* d_in, const int* in_sizes, int n_in,
                              void* d_out, int out_size, void* d_ws, size_t ws_size,
                              hipStream_t stream) {
    (void)in_sizes; (void)n_in; (void)out_size; (void)ws_size;
    const float* u      = (const float*)d_in[0];
    const float* v      = (const float*)d_in[1];
    const float* adj    = (const float*)d_in[2];
    const float* degree = (const float*)d_in[3];
    const float* uw     = (const float*)d_in[4];
    const float* vw     = (const float*)d_in[5];
    const float* bias   = (const float*)d_in[6];
    const int*   rp     = (const int*)d_in[7];
    u16*   ws  = (u16*)d_ws;                      // [0,1MB): pu; [1MB,2MB): pv
    float* wst = (float*)(ws + 2 * PACK_SIDE);    // [2MB, 66MB): top partials
    float* wsb = wst + (size_t)32 * NROWS * HID;  // [66MB, 130MB): bot partials
    float* out = (float*)d_out;

    k_prep<<<dim3(128, 2), 256, 0, stream>>>(u, v, uw, vw, rp, ws);
    k_main<<<dim3(1024),   256, 0, stream>>>(adj, ws, wst, wsb);
    k_fin <<<dim3(1024),   256, 0, stream>>>(degree, bias, wst, wsb, out);
}